// Round 9
// baseline (196.158 us; speedup 1.0000x reference)
//
#include <hip/hip_runtime.h>

#define B_SZ  4
#define N_TOK 4096   // H*W
#define CH    256
#define CR    32
#define SEG   512    // keys per wave (split-K segment), 8 waves/block
#define KT    32     // keys per iteration (2-deep pipelined)
#define NITER (SEG / KT)
#define LOG2E 1.44269504f
#define SHIFT2 (12.0f * 1.44269504f)   // softmax shift in exp2 domain (g pre-scaled by log2e)

typedef __attribute__((ext_vector_type(8))) short bf16x8;  // 8 bf16 = 4 VGPRs
typedef __attribute__((ext_vector_type(4))) float f32x4;

__device__ inline ushort f2bf(float x) {           // RNE fp32->bf16
    uint u = __float_as_uint(x);
    u += 0x7fff + ((u >> 16) & 1);
    return (ushort)(u >> 16);
}
__device__ inline uint pk2bf(float a, float b) {   // [bf16(b)|bf16(a)], truncate
    return __builtin_amdgcn_perm(__float_as_uint(b), __float_as_uint(a), 0x07060302);
}

// ---------- Kernel 0: weight prep — Wf/Wg/Wh -> transposed bf16 [32][256]; Wv -> [256][32] bf16 ----------
__global__ __launch_bounds__(256) void prep_kernel(
    const float* __restrict__ Wf, const float* __restrict__ Wg,
    const float* __restrict__ Wh, const float* __restrict__ Wv,
    ushort* __restrict__ wft, ushort* __restrict__ wgt,
    ushort* __restrict__ wht, ushort* __restrict__ wvt)
{
    int t = threadIdx.x, blk = blockIdx.x;
    if (blk < 3) {
        const float* W  = (blk == 0) ? Wf : (blk == 1) ? Wg : Wh;
        ushort*      Wt = (blk == 0) ? wft : (blk == 1) ? wgt : wht;
        int j = t & 31, half = t >> 5;
        ushort tmp[32];
        #pragma unroll
        for (int kk = 0; kk < 32; ++kk)
            tmp[kk] = f2bf(W[(half * 32 + kk) * CR + j]);
        ushort* dst = Wt + (size_t)j * CH + half * 32;
        #pragma unroll
        for (int k8 = 0; k8 < 4; ++k8)
            *(bf16x8*)(dst + k8 * 8) = *(bf16x8*)&tmp[k8 * 8];
    } else {
        ushort tmp[32];
        #pragma unroll
        for (int k = 0; k < CR; ++k) tmp[k] = f2bf(Wv[k * CH + t]);
        ushort* dst = wvt + (size_t)t * CR;
        #pragma unroll
        for (int k8 = 0; k8 < 4; ++k8)
            *(bf16x8*)(dst + k8 * 8) = *(bf16x8*)&tmp[k8 * 8];
    }
}

// ---------- Kernel A: MFMA projections, 4-way split-K. g is scaled by log2(e). ----------
__global__ __launch_bounds__(256) void proj_kernel(
    const float* __restrict__ x,
    const ushort* __restrict__ wft, const ushort* __restrict__ wgt, const ushort* __restrict__ wht,
    const float* __restrict__ bf_, const float* __restrict__ bg, const float* __restrict__ bh,
    ushort* __restrict__ fo, ushort* __restrict__ go, ushort* __restrict__ hto)
{
    __shared__ f32x4 accx[3][6][64];   // partial accs from waves 1..3 (18 KB)
    int t  = threadIdx.x;
    int wv = t >> 6, L = t & 63, nl = L & 15, Q = L >> 4;
    int row_t = blockIdx.x * 16;
    int b = row_t >> 12, tok0 = row_t & 4095;

    const float* xrow = x + (size_t)(row_t + nl) * CH;
    f32x4 A[6];
    #pragma unroll
    for (int i = 0; i < 6; ++i) A[i] = (f32x4){0.f, 0.f, 0.f, 0.f};

    #pragma unroll
    for (int c2 = 0; c2 < 2; ++c2) {
        int off = wv * 64 + c2 * 32 + Q * 8;
        float4 lo = *(const float4*)(xrow + off);
        float4 hi = *(const float4*)(xrow + off + 4);
        bf16x8 xa;
        xa[0] = (short)f2bf(lo.x); xa[1] = (short)f2bf(lo.y);
        xa[2] = (short)f2bf(lo.z); xa[3] = (short)f2bf(lo.w);
        xa[4] = (short)f2bf(hi.x); xa[5] = (short)f2bf(hi.y);
        xa[6] = (short)f2bf(hi.z); xa[7] = (short)f2bf(hi.w);

        bf16x8 wf0 = *(const bf16x8*)(wft + (size_t)nl * CH + off);
        bf16x8 wf1 = *(const bf16x8*)(wft + (size_t)(16 + nl) * CH + off);
        bf16x8 wg0 = *(const bf16x8*)(wgt + (size_t)nl * CH + off);
        bf16x8 wg1 = *(const bf16x8*)(wgt + (size_t)(16 + nl) * CH + off);
        bf16x8 wh0 = *(const bf16x8*)(wht + (size_t)nl * CH + off);
        bf16x8 wh1 = *(const bf16x8*)(wht + (size_t)(16 + nl) * CH + off);

        A[0] = __builtin_amdgcn_mfma_f32_16x16x32_bf16(xa, wf0, A[0], 0, 0, 0);
        A[1] = __builtin_amdgcn_mfma_f32_16x16x32_bf16(xa, wf1, A[1], 0, 0, 0);
        A[2] = __builtin_amdgcn_mfma_f32_16x16x32_bf16(xa, wg0, A[2], 0, 0, 0);
        A[3] = __builtin_amdgcn_mfma_f32_16x16x32_bf16(xa, wg1, A[3], 0, 0, 0);
        A[4] = __builtin_amdgcn_mfma_f32_16x16x32_bf16(wh0, xa, A[4], 0, 0, 0);  // h^T
        A[5] = __builtin_amdgcn_mfma_f32_16x16x32_bf16(wh1, xa, A[5], 0, 0, 0);
    }

    if (wv > 0) {
        #pragma unroll
        for (int i = 0; i < 6; ++i) accx[wv - 1][i][L] = A[i];
    }
    __syncthreads();
    if (wv == 0) {
        #pragma unroll
        for (int i = 0; i < 6; ++i) {
            f32x4 s0 = accx[0][i][L], s1 = accx[1][i][L], s2 = accx[2][i][L];
            A[i] = A[i] + s0 + s1 + s2;
        }
        float bF0 = bf_[nl], bF1 = bf_[16 + nl];
        float bG0 = bg[nl] * LOG2E, bG1 = bg[16 + nl] * LOG2E;
        #pragma unroll
        for (int r = 0; r < 4; ++r) {
            size_t ro = (size_t)(row_t + Q * 4 + r) * CR;
            fo[ro + nl]      = f2bf(A[0][r] + bF0);
            fo[ro + 16 + nl] = f2bf(A[1][r] + bF1);
            go[ro + nl]      = f2bf(fmaf(A[2][r], LOG2E, bG0));
            go[ro + 16 + nl] = f2bf(fmaf(A[3][r], LOG2E, bG1));
        }
        ushort* hb = hto + (size_t)b * CR * N_TOK + tok0 + nl;
        #pragma unroll
        for (int r = 0; r < 4; ++r) {
            int ch = Q * 4 + r;
            hb[(size_t)ch * N_TOK]        = f2bf(A[4][r] + bh[ch]);
            hb[(size_t)(16 + ch) * N_TOK] = f2bf(A[5][r] + bh[16 + ch]);
        }
    }
}

// ---------- Kernel B: attention — KT=32, double-buffered P, PV delayed one iteration ----------
// block = 512 thr = 8 waves; 32 queries/block; wave wv owns keys [wv*512, (wv+1)*512)
__global__ __launch_bounds__(512, 4) void attn_kernel(
    const ushort* __restrict__ f, const ushort* __restrict__ g,
    const ushort* __restrict__ ht, const ushort* __restrict__ wvt,
    const float* __restrict__ bv, const float* __restrict__ gamma,
    const float* __restrict__ x, float* __restrict__ out)
{
    // 37888 B shared. K-loop: pls[2][8][32][36] ushort (36864 B), row stride 36 ushorts
    // (18 words -> 16 bank bases, <=2-way on uint2 writes and bf16x8 reads).
    // Post-barrier alias: obuf[8][32][33] f32 (33792) + lbuf[8][32] (1024) + oc[32][48] (3072).
    __shared__ unsigned long long smem_raw[37888 / 8];
    ushort (*pls)[8][32][36] = (ushort (*)[8][32][36])smem_raw;
    float  (*obuf)[32][33]   = (float (*)[32][33])smem_raw;
    float  (*lbuf)[32]       = (float (*)[32])((char*)smem_raw + 33792);
    ushort (*oc)[48]         = (ushort (*)[48])((char*)smem_raw + 34816);

    int t  = threadIdx.x;
    int wv = t >> 6;
    int L  = t & 63;
    int nl = L & 15;
    int Q  = L >> 4;
    int b  = blockIdx.x >> 7;
    int q0 = (blockIdx.x & 127) * 32;

    const ushort* fb  = f  + (size_t)b * N_TOK * CR;
    const ushort* htb = ht + (size_t)b * CR * N_TOK;

    bf16x8 gB0 = *(const bf16x8*)(g + ((size_t)b * N_TOK + q0 + nl) * CR + Q * 8);
    bf16x8 gB1 = *(const bf16x8*)(g + ((size_t)b * N_TOK + q0 + 16 + nl) * CR + Q * 8);

    f32x4 acc00 = {0,0,0,0}, acc01 = {0,0,0,0};   // [qh][chhalf]
    f32x4 acc10 = {0,0,0,0}, acc11 = {0,0,0,0};
    const f32x4 zf = {0,0,0,0};
    float lsum0 = 0.f, lsum1 = 0.f;

    int k0 = wv * SEG;
    // iter-0 and iter-1 fragment loads
    bf16x8 Ac0 = *(const bf16x8*)(fb + (size_t)(k0 +      nl) * CR + Q * 8);
    bf16x8 Ac1 = *(const bf16x8*)(fb + (size_t)(k0 + 16 + nl) * CR + Q * 8);
    bf16x8 Bc0 = *(const bf16x8*)(htb + (size_t)nl * N_TOK + k0 + Q * 8);
    bf16x8 Bc1 = *(const bf16x8*)(htb + (size_t)(16 + nl) * N_TOK + k0 + Q * 8);
    bf16x8 An0 = *(const bf16x8*)(fb + (size_t)(k0 + KT +      nl) * CR + Q * 8);
    bf16x8 An1 = *(const bf16x8*)(fb + (size_t)(k0 + KT + 16 + nl) * CR + Q * 8);
    bf16x8 Bn0 = *(const bf16x8*)(htb + (size_t)nl * N_TOK + k0 + KT + Q * 8);
    bf16x8 Bn1 = *(const bf16x8*)(htb + (size_t)(16 + nl) * N_TOK + k0 + KT + Q * 8);

    // ---- iter 0: QK + exp + write P_0 to buf0 (no PV yet) ----
    {
        f32x4 s0 = __builtin_amdgcn_mfma_f32_16x16x32_bf16(Ac0, gB0, zf, 0, 0, 0);
        f32x4 s1 = __builtin_amdgcn_mfma_f32_16x16x32_bf16(Ac1, gB0, zf, 0, 0, 0);
        f32x4 s2 = __builtin_amdgcn_mfma_f32_16x16x32_bf16(Ac0, gB1, zf, 0, 0, 0);
        f32x4 s3 = __builtin_amdgcn_mfma_f32_16x16x32_bf16(Ac1, gB1, zf, 0, 0, 0);
        float p0, p1, p2, p3; uint2 w;
        p0=exp2f(s0[0]-SHIFT2); p1=exp2f(s0[1]-SHIFT2); p2=exp2f(s0[2]-SHIFT2); p3=exp2f(s0[3]-SHIFT2);
        lsum0 += (p0+p1)+(p2+p3); w.x=pk2bf(p0,p1); w.y=pk2bf(p2,p3);
        *(uint2*)&pls[0][wv][nl][Q * 4] = w;
        p0=exp2f(s1[0]-SHIFT2); p1=exp2f(s1[1]-SHIFT2); p2=exp2f(s1[2]-SHIFT2); p3=exp2f(s1[3]-SHIFT2);
        lsum0 += (p0+p1)+(p2+p3); w.x=pk2bf(p0,p1); w.y=pk2bf(p2,p3);
        *(uint2*)&pls[0][wv][nl][16 + Q * 4] = w;
        p0=exp2f(s2[0]-SHIFT2); p1=exp2f(s2[1]-SHIFT2); p2=exp2f(s2[2]-SHIFT2); p3=exp2f(s2[3]-SHIFT2);
        lsum1 += (p0+p1)+(p2+p3); w.x=pk2bf(p0,p1); w.y=pk2bf(p2,p3);
        *(uint2*)&pls[0][wv][16 + nl][Q * 4] = w;
        p0=exp2f(s3[0]-SHIFT2); p1=exp2f(s3[1]-SHIFT2); p2=exp2f(s3[2]-SHIFT2); p3=exp2f(s3[3]-SHIFT2);
        lsum1 += (p0+p1)+(p2+p3); w.x=pk2bf(p0,p1); w.y=pk2bf(p2,p3);
        *(uint2*)&pls[0][wv][16 + nl][16 + Q * 4] = w;
    }
    bf16x8 Bp0 = Bc0, Bp1 = Bc1;       // B of iter 0 for PV at iter 1
    Ac0 = An0; Ac1 = An1; Bc0 = Bn0; Bc1 = Bn1;

    #pragma unroll 2
    for (int it = 1; it < NITER; ++it) {
        int pb = (it - 1) & 1, cb = it & 1;
        // (a) read P_{it-1} A-frags first — writes completed an iteration ago, latency hidden below
        bf16x8 aP0 = *(const bf16x8*)&pls[pb][wv][     nl][Q * 8];
        bf16x8 aP1 = *(const bf16x8*)&pls[pb][wv][16 + nl][Q * 8];
        // (b) prefetch iter it+1 fragments
        int kn = k0 + ((it + 1 < NITER) ? it + 1 : 0) * KT;
        An0 = *(const bf16x8*)(fb + (size_t)(kn +      nl) * CR + Q * 8);
        An1 = *(const bf16x8*)(fb + (size_t)(kn + 16 + nl) * CR + Q * 8);
        Bn0 = *(const bf16x8*)(htb + (size_t)nl * N_TOK + kn + Q * 8);
        Bn1 = *(const bf16x8*)(htb + (size_t)(16 + nl) * N_TOK + kn + Q * 8);
        // (c) QK + exp + write P_it to buf cb
        f32x4 s0 = __builtin_amdgcn_mfma_f32_16x16x32_bf16(Ac0, gB0, zf, 0, 0, 0);
        f32x4 s1 = __builtin_amdgcn_mfma_f32_16x16x32_bf16(Ac1, gB0, zf, 0, 0, 0);
        f32x4 s2 = __builtin_amdgcn_mfma_f32_16x16x32_bf16(Ac0, gB1, zf, 0, 0, 0);
        f32x4 s3 = __builtin_amdgcn_mfma_f32_16x16x32_bf16(Ac1, gB1, zf, 0, 0, 0);
        float p0, p1, p2, p3; uint2 w;
        p0=exp2f(s0[0]-SHIFT2); p1=exp2f(s0[1]-SHIFT2); p2=exp2f(s0[2]-SHIFT2); p3=exp2f(s0[3]-SHIFT2);
        lsum0 += (p0+p1)+(p2+p3); w.x=pk2bf(p0,p1); w.y=pk2bf(p2,p3);
        *(uint2*)&pls[cb][wv][nl][Q * 4] = w;
        p0=exp2f(s1[0]-SHIFT2); p1=exp2f(s1[1]-SHIFT2); p2=exp2f(s1[2]-SHIFT2); p3=exp2f(s1[3]-SHIFT2);
        lsum0 += (p0+p1)+(p2+p3); w.x=pk2bf(p0,p1); w.y=pk2bf(p2,p3);
        *(uint2*)&pls[cb][wv][nl][16 + Q * 4] = w;
        p0=exp2f(s2[0]-SHIFT2); p1=exp2f(s2[1]-SHIFT2); p2=exp2f(s2[2]-SHIFT2); p3=exp2f(s2[3]-SHIFT2);
        lsum1 += (p0+p1)+(p2+p3); w.x=pk2bf(p0,p1); w.y=pk2bf(p2,p3);
        *(uint2*)&pls[cb][wv][16 + nl][Q * 4] = w;
        p0=exp2f(s3[0]-SHIFT2); p1=exp2f(s3[1]-SHIFT2); p2=exp2f(s3[2]-SHIFT2); p3=exp2f(s3[3]-SHIFT2);
        lsum1 += (p0+p1)+(p2+p3); w.x=pk2bf(p0,p1); w.y=pk2bf(p2,p3);
        *(uint2*)&pls[cb][wv][16 + nl][16 + Q * 4] = w;
        // (d) PV for iter it-1 (aP arrived long ago; fully decoupled from this iter's chain)
        acc00 = __builtin_amdgcn_mfma_f32_16x16x32_bf16(aP0, Bp0, acc00, 0, 0, 0);
        acc01 = __builtin_amdgcn_mfma_f32_16x16x32_bf16(aP0, Bp1, acc01, 0, 0, 0);
        acc10 = __builtin_amdgcn_mfma_f32_16x16x32_bf16(aP1, Bp0, acc10, 0, 0, 0);
        acc11 = __builtin_amdgcn_mfma_f32_16x16x32_bf16(aP1, Bp1, acc11, 0, 0, 0);
        // rotate
        Bp0 = Bc0; Bp1 = Bc1;
        Ac0 = An0; Ac1 = An1; Bc0 = Bn0; Bc1 = Bn1;
    }
    // drain: PV for iter NITER-1
    {
        int pb = (NITER - 1) & 1;
        bf16x8 aP0 = *(const bf16x8*)&pls[pb][wv][     nl][Q * 8];
        bf16x8 aP1 = *(const bf16x8*)&pls[pb][wv][16 + nl][Q * 8];
        acc00 = __builtin_amdgcn_mfma_f32_16x16x32_bf16(aP0, Bp0, acc00, 0, 0, 0);
        acc01 = __builtin_amdgcn_mfma_f32_16x16x32_bf16(aP0, Bp1, acc01, 0, 0, 0);
        acc10 = __builtin_amdgcn_mfma_f32_16x16x32_bf16(aP1, Bp0, acc10, 0, 0, 0);
        acc11 = __builtin_amdgcn_mfma_f32_16x16x32_bf16(aP1, Bp1, acc11, 0, 0, 0);
    }

    // prefetch epilogue residual x (cold HBM) before the barriers
    const float* xb = x + ((size_t)b * N_TOK + q0) * CH;
    int c0 = (wv * 2 + 0) * 16 + nl;
    int c1 = (wv * 2 + 1) * 16 + nl;
    float xr0[8], xr1[8];
    #pragma unroll
    for (int r = 0; r < 4; ++r) {
        xr0[r]     = xb[(Q * 4 + r) * CH + c0];
        xr0[4 + r] = xb[(16 + Q * 4 + r) * CH + c0];
        xr1[r]     = xb[(Q * 4 + r) * CH + c1];
        xr1[4 + r] = xb[(16 + Q * 4 + r) * CH + c1];
    }
    float gm = gamma[0];
    float bv0 = bv[c0], bv1 = bv[c1];

    lsum0 += __shfl_xor(lsum0, 16); lsum0 += __shfl_xor(lsum0, 32);
    lsum1 += __shfl_xor(lsum1, 16); lsum1 += __shfl_xor(lsum1, 32);

    __syncthreads();   // all pls reads done before aliasing as obuf
    #pragma unroll
    for (int r = 0; r < 4; ++r) {
        obuf[wv][     Q * 4 + r][nl]      = acc00[r];
        obuf[wv][     Q * 4 + r][16 + nl] = acc01[r];
        obuf[wv][16 + Q * 4 + r][nl]      = acc10[r];
        obuf[wv][16 + Q * 4 + r][16 + nl] = acc11[r];
    }
    if (L < 16) { lbuf[wv][nl] = lsum0; lbuf[wv][16 + nl] = lsum1; }
    __syncthreads();

    {
        int ch = t & 31, qb = t >> 5;   // 512 thr -> 2 (q,ch) each
        #pragma unroll
        for (int qq = qb; qq < 32; qq += 16) {
            float s = 0.f, Lq = 0.f;
            #pragma unroll
            for (int w = 0; w < 8; ++w) { s += obuf[w][qq][ch]; Lq += lbuf[w][qq]; }
            oc[qq][ch] = f2bf(s / Lq);
        }
    }
    __syncthreads();

    // fused epilogue: out = gamma*(o@Wv + bv) + x ; wave wv covers out-ch [wv*32, wv*32+32)
    bf16x8 aO0 = *(const bf16x8*)&oc[     nl][Q * 8];
    bf16x8 aO1 = *(const bf16x8*)&oc[16 + nl][Q * 8];
    float*       ob = out + ((size_t)b * N_TOK + q0) * CH;
    {
        bf16x8 bW0 = *(const bf16x8*)(wvt + (size_t)c0 * CR + Q * 8);
        bf16x8 bW1 = *(const bf16x8*)(wvt + (size_t)c1 * CR + Q * 8);
        f32x4 d00 = __builtin_amdgcn_mfma_f32_16x16x32_bf16(aO0, bW0, zf, 0, 0, 0);
        f32x4 d10 = __builtin_amdgcn_mfma_f32_16x16x32_bf16(aO1, bW0, zf, 0, 0, 0);
        f32x4 d01 = __builtin_amdgcn_mfma_f32_16x16x32_bf16(aO0, bW1, zf, 0, 0, 0);
        f32x4 d11 = __builtin_amdgcn_mfma_f32_16x16x32_bf16(aO1, bW1, zf, 0, 0, 0);
        #pragma unroll
        for (int r = 0; r < 4; ++r) {
            int qa = Q * 4 + r;
            ob[qa * CH + c0]        = fmaf(gm, d00[r] + bv0, xr0[r]);
            ob[(16 + qa) * CH + c0] = fmaf(gm, d10[r] + bv0, xr0[4 + r]);
            ob[qa * CH + c1]        = fmaf(gm, d01[r] + bv1, xr1[r]);
            ob[(16 + qa) * CH + c1] = fmaf(gm, d11[r] + bv1, xr1[4 + r]);
        }
    }
}

extern "C" void kernel_launch(void* const* d_in, const int* in_sizes, int n_in,
                              void* d_out, int out_size, void* d_ws, size_t ws_size,
                              hipStream_t stream) {
    const float* x     = (const float*)d_in[0];
    const float* Wf    = (const float*)d_in[1];
    const float* bf_   = (const float*)d_in[2];
    const float* Wg    = (const float*)d_in[3];
    const float* bg    = (const float*)d_in[4];
    const float* Wh    = (const float*)d_in[5];
    const float* bh    = (const float*)d_in[6];
    const float* Wv    = (const float*)d_in[7];
    const float* bv    = (const float*)d_in[8];
    const float* gamma = (const float*)d_in[9];
    float* out = (float*)d_out;

    const size_t T = (size_t)B_SZ * N_TOK * CR;     // 524288
    ushort* fo  = (ushort*)d_ws;
    ushort* go  = fo + T;
    ushort* hto = go + T;
    ushort* wvt = hto + T;                          // 256*32
    ushort* wft = wvt + CH * CR;                    // 32*256 each
    ushort* wgt = wft + CH * CR;
    ushort* wht = wgt + CH * CR;

    prep_kernel<<<4, 256, 0, stream>>>(Wf, Wg, Wh, Wv, wft, wgt, wht, wvt);
    proj_kernel<<<B_SZ * N_TOK / 16, 256, 0, stream>>>(x, wft, wgt, wht, bf_, bg, bh, fo, go, hto);
    attn_kernel<<<B_SZ * (N_TOK / 32), 512, 0, stream>>>(fo, go, hto, wvt, bv, gamma, x, out);
}

// Round 10
// 121.190 us; speedup vs baseline: 1.6186x; 1.6186x over previous
//
#include <hip/hip_runtime.h>

#define B_SZ  4
#define N_TOK 4096   // H*W
#define CH    256
#define CR    32
#define SEG   512    // keys per wave (split-K segment), 8 waves/block
#define KT    64     // keys per iteration
#define NITER (SEG / KT)
#define LOG2E 1.44269504f
#define SHIFT2 (12.0f * 1.44269504f)   // softmax shift in exp2 domain (g pre-scaled by log2e)

typedef __attribute__((ext_vector_type(8))) short bf16x8;  // 8 bf16 = 4 VGPRs
typedef __attribute__((ext_vector_type(4))) float f32x4;

__device__ inline ushort f2bf(float x) {           // RNE fp32->bf16
    uint u = __float_as_uint(x);
    u += 0x7fff + ((u >> 16) & 1);
    return (ushort)(u >> 16);
}
__device__ inline uint pk2bf(float a, float b) {   // [bf16(b)|bf16(a)], truncate
    return __builtin_amdgcn_perm(__float_as_uint(b), __float_as_uint(a), 0x07060302);
}
__device__ inline float fast_exp2(float x) {       // raw v_exp_f32 (1 instr) when available
#if __has_builtin(__builtin_amdgcn_exp2f)
    return __builtin_amdgcn_exp2f(x);
#else
    return exp2f(x);
#endif
}

// ---------- Kernel 0: weight prep — Wf/Wg/Wh -> transposed bf16 [32][256]; Wv -> [256][32] bf16 ----------
__global__ __launch_bounds__(256) void prep_kernel(
    const float* __restrict__ Wf, const float* __restrict__ Wg,
    const float* __restrict__ Wh, const float* __restrict__ Wv,
    ushort* __restrict__ wft, ushort* __restrict__ wgt,
    ushort* __restrict__ wht, ushort* __restrict__ wvt)
{
    int t = threadIdx.x, blk = blockIdx.x;
    if (blk < 3) {
        const float* W  = (blk == 0) ? Wf : (blk == 1) ? Wg : Wh;
        ushort*      Wt = (blk == 0) ? wft : (blk == 1) ? wgt : wht;
        int j = t & 31, half = t >> 5;
        ushort tmp[32];
        #pragma unroll
        for (int kk = 0; kk < 32; ++kk)
            tmp[kk] = f2bf(W[(half * 32 + kk) * CR + j]);
        ushort* dst = Wt + (size_t)j * CH + half * 32;
        #pragma unroll
        for (int k8 = 0; k8 < 4; ++k8)
            *(bf16x8*)(dst + k8 * 8) = *(bf16x8*)&tmp[k8 * 8];
    } else {
        ushort tmp[32];
        #pragma unroll
        for (int k = 0; k < CR; ++k) tmp[k] = f2bf(Wv[k * CH + t]);
        ushort* dst = wvt + (size_t)t * CR;
        #pragma unroll
        for (int k8 = 0; k8 < 4; ++k8)
            *(bf16x8*)(dst + k8 * 8) = *(bf16x8*)&tmp[k8 * 8];
    }
}

// ---------- Kernel A: MFMA projections, 4-way split-K. g is scaled by log2(e). ----------
__global__ __launch_bounds__(256) void proj_kernel(
    const float* __restrict__ x,
    const ushort* __restrict__ wft, const ushort* __restrict__ wgt, const ushort* __restrict__ wht,
    const float* __restrict__ bf_, const float* __restrict__ bg, const float* __restrict__ bh,
    ushort* __restrict__ fo, ushort* __restrict__ go, ushort* __restrict__ hto)
{
    __shared__ f32x4 accx[3][6][64];   // partial accs from waves 1..3 (18 KB)
    int t  = threadIdx.x;
    int wv = t >> 6, L = t & 63, nl = L & 15, Q = L >> 4;
    int row_t = blockIdx.x * 16;
    int b = row_t >> 12, tok0 = row_t & 4095;

    const float* xrow = x + (size_t)(row_t + nl) * CH;
    f32x4 A[6];
    #pragma unroll
    for (int i = 0; i < 6; ++i) A[i] = (f32x4){0.f, 0.f, 0.f, 0.f};

    #pragma unroll
    for (int c2 = 0; c2 < 2; ++c2) {
        int off = wv * 64 + c2 * 32 + Q * 8;
        float4 lo = *(const float4*)(xrow + off);
        float4 hi = *(const float4*)(xrow + off + 4);
        bf16x8 xa;
        xa[0] = (short)f2bf(lo.x); xa[1] = (short)f2bf(lo.y);
        xa[2] = (short)f2bf(lo.z); xa[3] = (short)f2bf(lo.w);
        xa[4] = (short)f2bf(hi.x); xa[5] = (short)f2bf(hi.y);
        xa[6] = (short)f2bf(hi.z); xa[7] = (short)f2bf(hi.w);

        bf16x8 wf0 = *(const bf16x8*)(wft + (size_t)nl * CH + off);
        bf16x8 wf1 = *(const bf16x8*)(wft + (size_t)(16 + nl) * CH + off);
        bf16x8 wg0 = *(const bf16x8*)(wgt + (size_t)nl * CH + off);
        bf16x8 wg1 = *(const bf16x8*)(wgt + (size_t)(16 + nl) * CH + off);
        bf16x8 wh0 = *(const bf16x8*)(wht + (size_t)nl * CH + off);
        bf16x8 wh1 = *(const bf16x8*)(wht + (size_t)(16 + nl) * CH + off);

        A[0] = __builtin_amdgcn_mfma_f32_16x16x32_bf16(xa, wf0, A[0], 0, 0, 0);
        A[1] = __builtin_amdgcn_mfma_f32_16x16x32_bf16(xa, wf1, A[1], 0, 0, 0);
        A[2] = __builtin_amdgcn_mfma_f32_16x16x32_bf16(xa, wg0, A[2], 0, 0, 0);
        A[3] = __builtin_amdgcn_mfma_f32_16x16x32_bf16(xa, wg1, A[3], 0, 0, 0);
        A[4] = __builtin_amdgcn_mfma_f32_16x16x32_bf16(wh0, xa, A[4], 0, 0, 0);  // h^T
        A[5] = __builtin_amdgcn_mfma_f32_16x16x32_bf16(wh1, xa, A[5], 0, 0, 0);
    }

    if (wv > 0) {
        #pragma unroll
        for (int i = 0; i < 6; ++i) accx[wv - 1][i][L] = A[i];
    }
    __syncthreads();
    if (wv == 0) {
        #pragma unroll
        for (int i = 0; i < 6; ++i) {
            f32x4 s0 = accx[0][i][L], s1 = accx[1][i][L], s2 = accx[2][i][L];
            A[i] = A[i] + s0 + s1 + s2;
        }
        float bF0 = bf_[nl], bF1 = bf_[16 + nl];
        float bG0 = bg[nl] * LOG2E, bG1 = bg[16 + nl] * LOG2E;
        #pragma unroll
        for (int r = 0; r < 4; ++r) {
            size_t ro = (size_t)(row_t + Q * 4 + r) * CR;
            fo[ro + nl]      = f2bf(A[0][r] + bF0);
            fo[ro + 16 + nl] = f2bf(A[1][r] + bF1);
            go[ro + nl]      = f2bf(fmaf(A[2][r], LOG2E, bG0));
            go[ro + 16 + nl] = f2bf(fmaf(A[3][r], LOG2E, bG1));
        }
        ushort* hb = hto + (size_t)b * CR * N_TOK + tok0 + nl;
        #pragma unroll
        for (int r = 0; r < 4; ++r) {
            int ch = Q * 4 + r;
            hb[(size_t)ch * N_TOK]        = f2bf(A[4][r] + bh[ch]);
            hb[(size_t)(16 + ch) * N_TOK] = f2bf(A[5][r] + bh[16 + ch]);
        }
    }
}

// ---------- Kernel B: attention — 8 waves x 512-key split-K, 32 queries/block, pipelined (R6 structure) ----------
__global__ __launch_bounds__(512, 4) void attn_kernel(
    const ushort* __restrict__ f, const ushort* __restrict__ g,
    const ushort* __restrict__ ht, const ushort* __restrict__ wvt,
    const float* __restrict__ bv, const float* __restrict__ gamma,
    const float* __restrict__ x, float* __restrict__ out)
{
    // 38912 B shared, aliased: K-loop = pls[8][32][76] ushort;
    // post-barrier = obuf[8][32][33] f32 (33792) + lbuf[8][32] (1024) + oc[32][48] ushort (3072)
    __shared__ unsigned long long smem_raw[38912 / 8];
    ushort (*pls)[32][76]  = (ushort (*)[32][76])smem_raw;
    float  (*obuf)[32][33] = (float (*)[32][33])smem_raw;
    float  (*lbuf)[32]     = (float (*)[32])((char*)smem_raw + 33792);
    ushort (*oc)[48]       = (ushort (*)[48])((char*)smem_raw + 34816);

    int t  = threadIdx.x;
    int wv = t >> 6;
    int L  = t & 63;
    int nl = L & 15;
    int Q  = L >> 4;
    int b  = blockIdx.x >> 7;
    int q0 = (blockIdx.x & 127) * 32;

    const ushort* fb  = f  + (size_t)b * N_TOK * CR;
    const ushort* htb = ht + (size_t)b * CR * N_TOK;

    bf16x8 gB0 = *(const bf16x8*)(g + ((size_t)b * N_TOK + q0 + nl) * CR + Q * 8);
    bf16x8 gB1 = *(const bf16x8*)(g + ((size_t)b * N_TOK + q0 + 16 + nl) * CR + Q * 8);

    f32x4 acc00 = {0,0,0,0}, acc01 = {0,0,0,0};   // [qh][chhalf]
    f32x4 acc10 = {0,0,0,0}, acc11 = {0,0,0,0};
    const f32x4 zf = {0,0,0,0};
    float lsum0 = 0.f, lsum1 = 0.f;

    // prefetch QK A-frags (f) for iter 0
    int key0 = wv * SEG;
    bf16x8 Ac0 = *(const bf16x8*)(fb + (size_t)(key0 +  0 + nl) * CR + Q * 8);
    bf16x8 Ac1 = *(const bf16x8*)(fb + (size_t)(key0 + 16 + nl) * CR + Q * 8);
    bf16x8 Ac2 = *(const bf16x8*)(fb + (size_t)(key0 + 32 + nl) * CR + Q * 8);
    bf16x8 Ac3 = *(const bf16x8*)(fb + (size_t)(key0 + 48 + nl) * CR + Q * 8);

    #pragma unroll 2
    for (int it = 0; it < NITER; ++it) {
        int kc = wv * SEG + it * KT;
        // issue ht B-frags now (consumed at end of body)
        const ushort* hk = htb + (size_t)nl * N_TOK + kc;
        bf16x8 b00 = *(const bf16x8*)(hk + Q * 8);
        bf16x8 b01 = *(const bf16x8*)(hk + (size_t)16 * N_TOK + Q * 8);
        bf16x8 b10 = *(const bf16x8*)(hk + 32 + Q * 8);
        bf16x8 b11 = *(const bf16x8*)(hk + (size_t)16 * N_TOK + 32 + Q * 8);
        // issue next iteration's A-frags (kept valid on last iter)
        int kn = wv * SEG + ((it + 1 < NITER) ? it + 1 : 0) * KT;
        const ushort* fn = fb + (size_t)kn * CR;
        bf16x8 An0 = *(const bf16x8*)(fn + (size_t)( 0 + nl) * CR + Q * 8);
        bf16x8 An1 = *(const bf16x8*)(fn + (size_t)(16 + nl) * CR + Q * 8);
        bf16x8 An2 = *(const bf16x8*)(fn + (size_t)(32 + nl) * CR + Q * 8);
        bf16x8 An3 = *(const bf16x8*)(fn + (size_t)(48 + nl) * CR + Q * 8);

        // QK^T for both query halves: S^T[key][query]
        f32x4 s00 = __builtin_amdgcn_mfma_f32_16x16x32_bf16(Ac0, gB0, zf, 0, 0, 0);
        f32x4 s01 = __builtin_amdgcn_mfma_f32_16x16x32_bf16(Ac1, gB0, zf, 0, 0, 0);
        f32x4 s02 = __builtin_amdgcn_mfma_f32_16x16x32_bf16(Ac2, gB0, zf, 0, 0, 0);
        f32x4 s03 = __builtin_amdgcn_mfma_f32_16x16x32_bf16(Ac3, gB0, zf, 0, 0, 0);
        f32x4 s10 = __builtin_amdgcn_mfma_f32_16x16x32_bf16(Ac0, gB1, zf, 0, 0, 0);
        f32x4 s11 = __builtin_amdgcn_mfma_f32_16x16x32_bf16(Ac1, gB1, zf, 0, 0, 0);
        f32x4 s12 = __builtin_amdgcn_mfma_f32_16x16x32_bf16(Ac2, gB1, zf, 0, 0, 0);
        f32x4 s13 = __builtin_amdgcn_mfma_f32_16x16x32_bf16(Ac3, gB1, zf, 0, 0, 0);

        // p = exp2(s - SHIFT2): one v_exp_f32 each; pack to bf16; wave-private LDS transpose
        #pragma unroll
        for (int qh = 0; qh < 2; ++qh) {
            f32x4 v0 = qh ? s10 : s00, v1 = qh ? s11 : s01;
            f32x4 v2 = qh ? s12 : s02, v3 = qh ? s13 : s03;
            int row = qh * 16 + nl;
            float p0 = fast_exp2(v0[0]-SHIFT2), p1 = fast_exp2(v0[1]-SHIFT2);
            float p2 = fast_exp2(v0[2]-SHIFT2), p3 = fast_exp2(v0[3]-SHIFT2);
            float s4 = ((p0+p1)+(p2+p3));
            uint2 w; w.x = pk2bf(p0,p1); w.y = pk2bf(p2,p3);
            *(uint2*)&pls[wv][row][ 0 + Q * 4] = w;
            p0 = fast_exp2(v1[0]-SHIFT2); p1 = fast_exp2(v1[1]-SHIFT2);
            p2 = fast_exp2(v1[2]-SHIFT2); p3 = fast_exp2(v1[3]-SHIFT2);
            s4 += ((p0+p1)+(p2+p3));
            w.x = pk2bf(p0,p1); w.y = pk2bf(p2,p3);
            *(uint2*)&pls[wv][row][16 + Q * 4] = w;
            p0 = fast_exp2(v2[0]-SHIFT2); p1 = fast_exp2(v2[1]-SHIFT2);
            p2 = fast_exp2(v2[2]-SHIFT2); p3 = fast_exp2(v2[3]-SHIFT2);
            s4 += ((p0+p1)+(p2+p3));
            w.x = pk2bf(p0,p1); w.y = pk2bf(p2,p3);
            *(uint2*)&pls[wv][row][32 + Q * 4] = w;
            p0 = fast_exp2(v3[0]-SHIFT2); p1 = fast_exp2(v3[1]-SHIFT2);
            p2 = fast_exp2(v3[2]-SHIFT2); p3 = fast_exp2(v3[3]-SHIFT2);
            s4 += ((p0+p1)+(p2+p3));
            w.x = pk2bf(p0,p1); w.y = pk2bf(p2,p3);
            *(uint2*)&pls[wv][row][48 + Q * 4] = w;
            if (qh) lsum1 += s4; else lsum0 += s4;
        }

        // read back as PV A-frags (DS is in-order per wave: RAW safe, compiler emits lgkmcnt)
        bf16x8 aP00 = *(const bf16x8*)&pls[wv][     nl][ 0 + Q * 8];
        bf16x8 aP01 = *(const bf16x8*)&pls[wv][     nl][32 + Q * 8];
        bf16x8 aP10 = *(const bf16x8*)&pls[wv][16 + nl][ 0 + Q * 8];
        bf16x8 aP11 = *(const bf16x8*)&pls[wv][16 + nl][32 + Q * 8];

        acc00 = __builtin_amdgcn_mfma_f32_16x16x32_bf16(aP00, b00, acc00, 0, 0, 0);
        acc01 = __builtin_amdgcn_mfma_f32_16x16x32_bf16(aP00, b01, acc01, 0, 0, 0);
        acc10 = __builtin_amdgcn_mfma_f32_16x16x32_bf16(aP10, b00, acc10, 0, 0, 0);
        acc11 = __builtin_amdgcn_mfma_f32_16x16x32_bf16(aP10, b01, acc11, 0, 0, 0);
        acc00 = __builtin_amdgcn_mfma_f32_16x16x32_bf16(aP01, b10, acc00, 0, 0, 0);
        acc01 = __builtin_amdgcn_mfma_f32_16x16x32_bf16(aP01, b11, acc01, 0, 0, 0);
        acc10 = __builtin_amdgcn_mfma_f32_16x16x32_bf16(aP11, b10, acc10, 0, 0, 0);
        acc11 = __builtin_amdgcn_mfma_f32_16x16x32_bf16(aP11, b11, acc11, 0, 0, 0);

        Ac0 = An0; Ac1 = An1; Ac2 = An2; Ac3 = An3;
    }

    lsum0 += __shfl_xor(lsum0, 16); lsum0 += __shfl_xor(lsum0, 32);
    lsum1 += __shfl_xor(lsum1, 16); lsum1 += __shfl_xor(lsum1, 32);

    __syncthreads();   // all pls reads done before aliasing as obuf
    #pragma unroll
    for (int r = 0; r < 4; ++r) {
        obuf[wv][     Q * 4 + r][nl]      = acc00[r];
        obuf[wv][     Q * 4 + r][16 + nl] = acc01[r];
        obuf[wv][16 + Q * 4 + r][nl]      = acc10[r];
        obuf[wv][16 + Q * 4 + r][16 + nl] = acc11[r];
    }
    if (L < 16) { lbuf[wv][nl] = lsum0; lbuf[wv][16 + nl] = lsum1; }
    __syncthreads();

    {
        int ch = t & 31, qb = t >> 5;   // 512 thr -> 2 (q,ch) each
        #pragma unroll
        for (int qq = qb; qq < 32; qq += 16) {
            float s = 0.f, Lq = 0.f;
            #pragma unroll
            for (int w = 0; w < 8; ++w) { s += obuf[w][qq][ch]; Lq += lbuf[w][qq]; }
            oc[qq][ch] = f2bf(s / Lq);
        }
    }
    __syncthreads();

    // fused epilogue: out = gamma*(o@Wv + bv) + x ; wave wv covers out-ch [wv*32, wv*32+32)
    bf16x8 aO0 = *(const bf16x8*)&oc[     nl][Q * 8];
    bf16x8 aO1 = *(const bf16x8*)&oc[16 + nl][Q * 8];
    float gm = gamma[0];
    const float* xb = x   + ((size_t)b * N_TOK + q0) * CH;
    float*       ob = out + ((size_t)b * N_TOK + q0) * CH;
    #pragma unroll
    for (int i = 0; i < 2; ++i) {
        int nb = wv * 2 + i;
        bf16x8 bW = *(const bf16x8*)(wvt + (size_t)(nb * 16 + nl) * CR + Q * 8);
        f32x4 d0 = __builtin_amdgcn_mfma_f32_16x16x32_bf16(aO0, bW, zf, 0, 0, 0);
        f32x4 d1 = __builtin_amdgcn_mfma_f32_16x16x32_bf16(aO1, bW, zf, 0, 0, 0);
        int c = nb * 16 + nl;
        float bvc = bv[c];
        #pragma unroll
        for (int r = 0; r < 4; ++r) {
            int qa = Q * 4 + r;
            ob[qa * CH + c]        = fmaf(gm, d0[r] + bvc, xb[qa * CH + c]);
            ob[(16 + qa) * CH + c] = fmaf(gm, d1[r] + bvc, xb[(16 + qa) * CH + c]);
        }
    }
}

extern "C" void kernel_launch(void* const* d_in, const int* in_sizes, int n_in,
                              void* d_out, int out_size, void* d_ws, size_t ws_size,
                              hipStream_t stream) {
    const float* x     = (const float*)d_in[0];
    const float* Wf    = (const float*)d_in[1];
    const float* bf_   = (const float*)d_in[2];
    const float* Wg    = (const float*)d_in[3];
    const float* bg    = (const float*)d_in[4];
    const float* Wh    = (const float*)d_in[5];
    const float* bh    = (const float*)d_in[6];
    const float* Wv    = (const float*)d_in[7];
    const float* bv    = (const float*)d_in[8];
    const float* gamma = (const float*)d_in[9];
    float* out = (float*)d_out;

    const size_t T = (size_t)B_SZ * N_TOK * CR;     // 524288
    ushort* fo  = (ushort*)d_ws;
    ushort* go  = fo + T;
    ushort* hto = go + T;
    ushort* wvt = hto + T;                          // 256*32
    ushort* wft = wvt + CH * CR;                    // 32*256 each
    ushort* wgt = wft + CH * CR;
    ushort* wht = wgt + CH * CR;

    prep_kernel<<<4, 256, 0, stream>>>(Wf, Wg, Wh, Wv, wft, wgt, wht, wvt);
    proj_kernel<<<B_SZ * N_TOK / 16, 256, 0, stream>>>(x, wft, wgt, wht, bf_, bg, bh, fo, go, hto);
    attn_kernel<<<B_SZ * (N_TOK / 32), 512, 0, stream>>>(fo, go, hto, wvt, bv, gamma, x, out);
}